// Round 1
// baseline (360.822 us; speedup 1.0000x reference)
//
#include <hip/hip_runtime.h>

#define HH 512
#define WW 512
#define HW (HH*WW)
#define EPV 1e-20f

// Box window for center (y,x): rows y-3..y+4, cols x-3..x+4, zero-padded.
// 4 cols/lane (float4). Horizontal windows via prefix/suffix exchange:
//   winC(u) = sum_{d=-3..+4} v(u+d)  (centered, 7 bp)  -- mean window
//   winR(u) = sum_{d=1..8}  v(u+d)  (right,    5 bp)  -- h for output col x0+u
// Vertical = register rings (depth 8), sliding sums.
// R10: ncc splits j across a 4-wave workgroup (1 ring/wave -> <=128 regs,
// 16 waves/CU) with LDS max-combine; prep segs 32->16 rows; memset folded
// into prep; fixed sii/sjj off-by-one row (prefetch now AFTER emit).

__device__ __forceinline__ float bpl(int addr, float v) {
    return __int_as_float(__builtin_amdgcn_ds_bpermute(addr, __float_as_int(v)));
}
__device__ __forceinline__ int rcl(int r) { return min(max(r, 0), HH - 1); }

// centered window over strip cols u=4*lane+e
__device__ __forceinline__ float4 winC(float4 v, int aL1, int aR1) {
    float pre2 = v.x + v.y, pre3 = pre2 + v.z, g = pre3 + v.w;
    float suf2 = v.z + v.w, suf3 = v.y + suf2;
    float Ls1 = bpl(aL1, v.w), Ls2 = bpl(aL1, suf2), Ls3 = bpl(aL1, suf3);
    float Rp1 = bpl(aR1, v.x), Rp2 = bpl(aR1, pre2), Rp3 = bpl(aR1, pre3);
    float Rg  = bpl(aR1, g);
    return make_float4(Ls3 + g + Rp1, Ls2 + g + Rp2, Ls1 + g + Rp3, g + Rg);
}
// right-leaning window (serves output col x0+u)
__device__ __forceinline__ float4 winR(float4 v, int aR1, int aR2) {
    float pre2 = v.x + v.y, pre3 = pre2 + v.z, g = pre3 + v.w;
    float suf2 = v.z + v.w, suf3 = v.y + suf2;
    float G1 = bpl(aR1, g);
    float P1 = bpl(aR2, v.x), P2 = bpl(aR2, pre2), P3 = bpl(aR2, pre3);
    float G2 = bpl(aR2, g);
    return make_float4(suf3 + G1 + P1, suf2 + G1 + P2, v.w + G1 + P3, G1 + G2);
}

// ---------------- prep: raw image -> centered (ac) + variance box (sii) ----
// One wave per (z, strip, 16-row seg). Strips x0 = {0,232,468}. 31 steps.
__global__ __launch_bounds__(64, 4) void prep_f4(
    const float* __restrict__ outs, const float* __restrict__ labs,
    float* __restrict__ ac, float* __restrict__ sii, float* __restrict__ outbuf)
{
    const int l  = threadIdx.x;
    if (blockIdx.x == 0 && blockIdx.y == 0 && blockIdx.z == 0 && l < 25)
        outbuf[l] = 0.f;                      // replaces hipMemsetAsync
    const int s  = blockIdx.x;
    const int x0 = (s == 0) ? 0 : (s == 1 ? 232 : 468);
    const int y0 = 16 * blockIdx.y;
    const int z  = blockIdx.z;

    const float* src = (z < 24) ? outs + z * HW : labs + (z - 24) * HW;
    float* acd = ac  + z * HW;
    float* sid = sii + z * HW;

    const int   bcol0 = x0 - 4 + 4 * l;
    const int   bcol  = min(max(bcol0, 0), WW - 4);
    const float cmask = (bcol0 >= 0 && bcol0 <= WW - 4) ? 1.f : 0.f;
    const int   ocol0 = x0 + 4 * l;
    const int   aL1 = ((l - 1) & 63) << 2;
    const int   aR1 = ((l + 1) & 63) << 2;
    const int   aR2 = ((l + 2) & 63) << 2;
    const bool stA = (l >= 1 && l <= 60 && bcol0 >= 0 && bcol0 <= WW - 4);
    const bool stS = (l >= ((x0 == 0) ? 0 : 1) && l <= 59 && ocol0 <= WW - 4);

    float4 fifo[2];
    fifo[0] = *(const float4*)&src[rcl(y0 - 7) * WW + bcol];
    fifo[1] = *(const float4*)&src[rcl(y0 - 6) * WW + bcol];

    float4 araw[4], haR[8], hsR[8];
    float4 VA = make_float4(0,0,0,0), VS = make_float4(0,0,0,0);
    #pragma unroll
    for (int k = 0; k < 4; ++k) araw[k] = make_float4(0,0,0,0);
    #pragma unroll
    for (int k = 0; k < 8; ++k) { haR[k] = make_float4(0,0,0,0); hsR[k] = make_float4(0,0,0,0); }

    auto step = [&](int t) {
        const int   k  = t & 7;
        const int   r  = y0 - 7 + t;
        const float rm = (r >= 0 && r < HH) ? cmask : 0.f;
        float4 raw = fifo[t & 1];
        float4 av  = make_float4(raw.x*rm, raw.y*rm, raw.z*rm, raw.w*rm);
        if (t <= 28) fifo[t & 1] = *(const float4*)&src[rcl(r + 2) * WW + bcol];

        float4 h = winC(av, aL1, aR1);
        VA.x += h.x - haR[k].x; VA.y += h.y - haR[k].y;
        VA.z += h.z - haR[k].z; VA.w += h.w - haR[k].w;
        haR[k] = h;

        float4 aold = araw[t & 3]; araw[t & 3] = av;   // row c = r-4
        const int   c  = r - 4;
        const float cm = (c >= 0 && c < HH) ? cmask : 0.f;
        float4 acv = make_float4((aold.x - VA.x*(1.f/64.f))*cm,
                                 (aold.y - VA.y*(1.f/64.f))*cm,
                                 (aold.z - VA.z*(1.f/64.f))*cm,
                                 (aold.w - VA.w*(1.f/64.f))*cm);
        if (t >= 11 && t <= 26) {
            if (stA) *(float4*)&acd[c * WW + bcol0] = acv;
        }
        float4 sq = make_float4(acv.x*acv.x, acv.y*acv.y, acv.z*acv.z, acv.w*acv.w);
        float4 h2 = winR(sq, aR1, aR2);
        VS.x += h2.x - hsR[k].x; VS.y += h2.y - hsR[k].y;
        VS.z += h2.z - hsR[k].z; VS.w += h2.w - hsR[k].w;
        hsR[k] = h2;
        if (t >= 15) {
            const int y = c - 4;                        // y in [y0, y0+15]
            if (stS) *(float4*)&sid[y * WW + ocol0] =
                make_float4(fmaxf(VS.x, EPV), fmaxf(VS.y, EPV),
                            fmaxf(VS.z, EPV), fmaxf(VS.w, EPV));
        }
    };
    #pragma unroll
    for (int t = 0; t < 31; ++t) step(t);
}

// ---------------- main: product boxes, j split across 4 waves --------------
// One 256-thread block (4 waves) per (z=b*6+i, strip x0={0,240,480}, 16-row
// seg). Wave w handles label j=w: one ring -> ~100 regs -> 16 waves/CU.
// Per-pixel cc_j exchanged via double-buffered LDS; max-combine round-robin.
__global__ __launch_bounds__(256, 4) void ncc_f4(
    const float* __restrict__ ac, const float* __restrict__ sii,
    float* __restrict__ out)
{
    __shared__ float4 xch[2][4][64];
    const int tid = threadIdx.x;
    const int l   = tid & 63;
    const int wid = tid >> 6;                // = j
    const int x0 = 240 * blockIdx.x;
    const int y0 = 16 * blockIdx.y;
    const int z  = blockIdx.z;               // b*6 + i
    const int b  = z / 6;

    const float* acp = ac  + z * HW;
    const float* sip = sii + z * HW;
    const float* bcp = ac  + (24 + b * 4 + wid) * HW;
    const float* sjp = sii + (24 + b * 4 + wid) * HW;

    const int   bcol0 = x0 - 4 + 4 * l;
    const int   bcol  = min(max(bcol0, 0), WW - 4);
    const float cmask = (bcol0 >= 0 && bcol0 <= WW - 4) ? 1.f : 0.f;
    const int   ocol0 = x0 + 4 * l;
    const int   ocol  = min(ocol0, WW - 4);
    const float om    = (l <= 59 && ocol0 <= WW - 4) ? 1.f : 0.f;
    const int   aR1 = ((l + 1) & 63) << 2;
    const int   aR2 = ((l + 2) & 63) << 2;

    float4 fa[2], fb[2];
    {
        const int r0 = rcl(y0 - 3), r1 = rcl(y0 - 2);
        fa[0] = *(const float4*)&acp[r0 * WW + bcol];
        fa[1] = *(const float4*)&acp[r1 * WW + bcol];
        fb[0] = *(const float4*)&bcp[r0 * WW + bcol];
        fb[1] = *(const float4*)&bcp[r1 * WW + bcol];
    }

    float4 ring[8];
    #pragma unroll
    for (int k = 0; k < 8; ++k) ring[k] = make_float4(0,0,0,0);
    float4 VS  = make_float4(0,0,0,0);
    float4 psi = make_float4(0,0,0,0), psj = make_float4(0,0,0,0);
    float4 xs  = make_float4(0,0,0,0);

    #pragma unroll
    for (int t = 0; t < 24; ++t) {
        if (t < 23) {                        // compute phase
            const int   k  = t & 7;
            const int   c  = y0 - 3 + t;
            const float rm = (c >= 0 && c < HH) ? cmask : 0.f;
            float4 av = fa[t & 1];
            av = make_float4(av.x*rm, av.y*rm, av.z*rm, av.w*rm);
            float4 bv = fb[t & 1];
            if (t <= 20) {
                const int rn = rcl(c + 2);
                fa[t & 1] = *(const float4*)&acp[rn * WW + bcol];
                fb[t & 1] = *(const float4*)&bcp[rn * WW + bcol];
            }
            float4 h = winR(make_float4(av.x*bv.x, av.y*bv.y, av.z*bv.z, av.w*bv.w),
                            aR1, aR2);
            VS.x += h.x - ring[k].x; VS.y += h.y - ring[k].y;
            VS.z += h.z - ring[k].z; VS.w += h.w - ring[k].w;
            ring[k] = h;
            if (t >= 7) {
                // cc_j for row y = y0+t-7; psi/psj hold row y (loaded LAST step)
                float4 val;
                val.x = VS.x * __frsqrt_rn(fmaxf(psi.x * psj.x, 1e-37f));
                val.y = VS.y * __frsqrt_rn(fmaxf(psi.y * psj.y, 1e-37f));
                val.z = VS.z * __frsqrt_rn(fmaxf(psi.z * psj.z, 1e-37f));
                val.w = VS.w * __frsqrt_rn(fmaxf(psi.w * psj.w, 1e-37f));
                xch[t & 1][wid][l] = val;
            }
            if (t >= 6 && t <= 21) {         // prefetch for NEXT step's emit
                const int yn = y0 + t - 6;
                psi = *(const float4*)&sip[yn * WW + ocol];
                psj = *(const float4*)&sjp[yn * WW + ocol];
            }
        }
        __syncthreads();
        // combine step t-1's row (double-buffered slot), round-robin over waves
        if (t >= 8 && ((t - 1) & 3) == wid) {
            const int s2 = (t - 1) & 1;
            float4 v0 = xch[s2][0][l], v1 = xch[s2][1][l];
            float4 v2 = xch[s2][2][l], v3 = xch[s2][3][l];
            float mmx = fmaxf(fmaxf(fmaxf(v0.x, v1.x), fmaxf(v2.x, v3.x)), -1.f);
            float mmy = fmaxf(fmaxf(fmaxf(v0.y, v1.y), fmaxf(v2.y, v3.y)), -1.f);
            float mmz = fmaxf(fmaxf(fmaxf(v0.z, v1.z), fmaxf(v2.z, v3.z)), -1.f);
            float mmw = fmaxf(fmaxf(fmaxf(v0.w, v1.w), fmaxf(v2.w, v3.w)), -1.f);
            xs.x += om * (1.f - fminf(mmx, 1.f));
            xs.y += om * (1.f - fminf(mmy, 1.f));
            xs.z += om * (1.f - fminf(mmz, 1.f));
            xs.w += om * (1.f - fminf(mmw, 1.f));
        }
    }

    float xt = xs.x + xs.y + xs.z + xs.w;
    #pragma unroll
    for (int off = 32; off > 0; off >>= 1) xt += __shfl_down(xt, off);
    if (l == 0) {
        atomicAdd(&out[1 + z], xt * (1.f / (float)HW));
        atomicAdd(&out[0],     xt * (1.f / (24.f * (float)HW)));
    }
}

extern "C" void kernel_launch(void* const* d_in, const int* in_sizes, int n_in,
                              void* d_out, int out_size, void* d_ws, size_t ws_size,
                              hipStream_t stream) {
    const float* outs = (const float*)d_in[0];   // (4,6,512,512)
    const float* labs = (const float*)d_in[1];   // (4,4,512,512)
    float* out = (float*)d_out;                  // 25 floats
    float* ws  = (float*)d_ws;

    float* acw  = ws;                 // 40*HW (a:0..23, b:24..39)
    float* siiw = ws + 40 * HW;       // 40*HW

    // prep: 3 strips x 32 segs(16 rows) x 40 images (also zeroes out)
    prep_f4<<<dim3(3, 32, 40), 64, 0, stream>>>(outs, labs, acw, siiw, out);
    // main: 3 strips x 32 segs(16 rows) x 24 (b,i), 4 waves (one per j)
    ncc_f4<<<dim3(3, 32, 24), 256, 0, stream>>>(acw, siiw, out);
}

// Round 2
// 171.067 us; speedup vs baseline: 2.1092x; 2.1092x over previous
//
#include <hip/hip_runtime.h>

#define HH 512
#define WW 512
#define HW (HH*WW)
#define EPV 1e-20f

// Box window for center (y,x): rows y-3..y+4, cols x-3..x+4, zero-padded.
// 4 cols/lane (float4). Horizontal windows via prefix/suffix exchange:
//   winC(u) = sum_{d=-3..+4} v(u+d)  (centered, 7 bp)  -- mean window
//   winR(u) = sum_{d=1..8}  v(u+d)  (right,    5 bp)  -- box for out col x0+u
// Vertical = register rings (depth 8) of RAW values (vertical-first);
// horizontal winR applied only on emit rows (linear operators commute).
// R11: barrier-free (R10 regression root-caused to per-step __syncthreads
// vmcnt-drain); 4 j/wave ILP restored; single-batch grids (no straggler
// batch); rolled 8-step loop bodies (I-cache); rsqrt precomputed in prep;
// off-by-one sii/sjj row fix kept (absmax 0.0).

__device__ __forceinline__ float bpl(int addr, float v) {
    return __int_as_float(__builtin_amdgcn_ds_bpermute(addr, __float_as_int(v)));
}
__device__ __forceinline__ int rcl(int r) { return min(max(r, 0), HH - 1); }

// centered window over strip cols u=4*lane+e
__device__ __forceinline__ float4 winC(float4 v, int aL1, int aR1) {
    float pre2 = v.x + v.y, pre3 = pre2 + v.z, g = pre3 + v.w;
    float suf2 = v.z + v.w, suf3 = v.y + suf2;
    float Ls1 = bpl(aL1, v.w), Ls2 = bpl(aL1, suf2), Ls3 = bpl(aL1, suf3);
    float Rp1 = bpl(aR1, v.x), Rp2 = bpl(aR1, pre2), Rp3 = bpl(aR1, pre3);
    float Rg  = bpl(aR1, g);
    return make_float4(Ls3 + g + Rp1, Ls2 + g + Rp2, Ls1 + g + Rp3, g + Rg);
}
// right-leaning window (serves output col x0+u)
__device__ __forceinline__ float4 winR(float4 v, int aR1, int aR2) {
    float pre2 = v.x + v.y, pre3 = pre2 + v.z, g = pre3 + v.w;
    float suf2 = v.z + v.w, suf3 = v.y + suf2;
    float G1 = bpl(aR1, g);
    float P1 = bpl(aR2, v.x), P2 = bpl(aR2, pre2), P3 = bpl(aR2, pre3);
    float G2 = bpl(aR2, g);
    return make_float4(suf3 + G1 + P1, suf2 + G1 + P2, v.w + G1 + P3, G1 + G2);
}

// ---------------- prep: raw image -> centered (ac) + 1/sqrt(var box) ------
// One wave per (z, strip, 32-row seg). Strips x0 = {0,232,468}. 48 steps
// (rolled 6x8). Vertical-first for the variance path.
__global__ __launch_bounds__(64) void prep_f4(
    const float* __restrict__ outs, const float* __restrict__ labs,
    float* __restrict__ ac, float* __restrict__ rs, float* __restrict__ outbuf)
{
    const int l  = threadIdx.x;
    if (blockIdx.x == 0 && blockIdx.y == 0 && blockIdx.z == 0 && l < 25)
        outbuf[l] = 0.f;                      // replaces hipMemsetAsync
    const int s  = blockIdx.x;
    const int x0 = (s == 0) ? 0 : (s == 1 ? 232 : 468);
    const int y0 = 32 * blockIdx.y;
    const int z  = blockIdx.z;

    const float* src = (z < 24) ? outs + z * HW : labs + (z - 24) * HW;
    float* acd = ac + z * HW;
    float* rsd = rs + z * HW;

    const int   bcol0 = x0 - 4 + 4 * l;
    const int   bcol  = min(max(bcol0, 0), WW - 4);
    const float cmask = (bcol0 >= 0 && bcol0 <= WW - 4) ? 1.f : 0.f;
    const int   ocol0 = x0 + 4 * l;
    const int   aL1 = ((l - 1) & 63) << 2;
    const int   aR1 = ((l + 1) & 63) << 2;
    const int   aR2 = ((l + 2) & 63) << 2;
    const bool stA = (l >= 1 && l <= 60 && bcol0 >= 0 && bcol0 <= WW - 4);
    const bool stS = (l >= ((x0 == 0) ? 0 : 1) && l <= 59 && ocol0 <= WW - 4);

    float4 fifo[2];
    fifo[0] = *(const float4*)&src[rcl(y0 - 7) * WW + bcol];
    fifo[1] = *(const float4*)&src[rcl(y0 - 6) * WW + bcol];

    float4 araw[4], haR[8], rgS[8];
    float4 VA = make_float4(0,0,0,0), Vq = make_float4(0,0,0,0);
    #pragma unroll
    for (int k = 0; k < 4; ++k) araw[k] = make_float4(0,0,0,0);
    #pragma unroll
    for (int k = 0; k < 8; ++k) { haR[k] = make_float4(0,0,0,0); rgS[k] = make_float4(0,0,0,0); }

    auto step = [&](const int t, const int kk) {
        const int   r  = y0 - 7 + t;
        const float rm = (r >= 0 && r < HH) ? cmask : 0.f;
        float4 raw = fifo[kk & 1];
        float4 av  = make_float4(raw.x*rm, raw.y*rm, raw.z*rm, raw.w*rm);
        if (t <= 45) fifo[kk & 1] = *(const float4*)&src[rcl(r + 2) * WW + bcol];

        float4 h = winC(av, aL1, aR1);
        VA.x += h.x - haR[kk].x; VA.y += h.y - haR[kk].y;
        VA.z += h.z - haR[kk].z; VA.w += h.w - haR[kk].w;
        haR[kk] = h;

        float4 aold = araw[kk & 3]; araw[kk & 3] = av;   // row c = r-4
        const int   c  = r - 4;
        const float cm = (c >= 0 && c < HH) ? cmask : 0.f;
        float4 acv = make_float4((aold.x - VA.x*(1.f/64.f))*cm,
                                 (aold.y - VA.y*(1.f/64.f))*cm,
                                 (aold.z - VA.z*(1.f/64.f))*cm,
                                 (aold.w - VA.w*(1.f/64.f))*cm);
        if (t >= 11 && t <= 42) {
            if (stA) *(float4*)&acd[c * WW + bcol0] = acv;
        }
        float4 sq = make_float4(acv.x*acv.x, acv.y*acv.y, acv.z*acv.z, acv.w*acv.w);
        Vq.x += sq.x - rgS[kk].x; Vq.y += sq.y - rgS[kk].y;
        Vq.z += sq.z - rgS[kk].z; Vq.w += sq.w - rgS[kk].w;
        rgS[kk] = sq;
        if (t >= 15 && t <= 46) {                        // emit row y = c-4
            const int y = c - 4;                         // y in [y0, y0+31]
            float4 h2 = winR(Vq, aR1, aR2);              // box sum of sq
            if (stS) *(float4*)&rsd[y * WW + ocol0] = make_float4(
                __frsqrt_rn(fmaxf(h2.x, EPV)), __frsqrt_rn(fmaxf(h2.y, EPV)),
                __frsqrt_rn(fmaxf(h2.z, EPV)), __frsqrt_rn(fmaxf(h2.w, EPV)));
        }
    };
    for (int it = 0; it < 6; ++it) {
        const int t0 = it * 8;
        #pragma unroll
        for (int kk = 0; kk < 8; ++kk) step(t0 + kk, kk);
    }
}

// ---------------- main: product boxes, all 4 j per wave, barrier-free -----
// One wave per (z=b*6+i, strip x0={0,240,480}, 19-row seg). 26 steps
// (rolled 3x8 + 2 tail). 1944 waves -> single residency batch at 8 waves/CU.
__global__ __launch_bounds__(64) void ncc_f4(
    const float* __restrict__ ac, const float* __restrict__ rs,
    float* __restrict__ out)
{
    const int l  = threadIdx.x;
    const int x0 = 240 * blockIdx.x;
    const int y0 = 19 * blockIdx.y;
    const int z  = blockIdx.z;               // b*6 + i
    const int b  = z / 6;

    const float* acp = ac + z * HW;
    const float* sip = rs + z * HW;
    const float* bcp[4]; const float* sjp[4];
    #pragma unroll
    for (int j = 0; j < 4; ++j) {
        bcp[j] = ac + (24 + b * 4 + j) * HW;
        sjp[j] = rs + (24 + b * 4 + j) * HW;
    }

    const int   bcol0 = x0 - 4 + 4 * l;
    const int   bcol  = min(max(bcol0, 0), WW - 4);
    const float cmask = (bcol0 >= 0 && bcol0 <= WW - 4) ? 1.f : 0.f;
    const int   ocol0 = x0 + 4 * l;
    const int   ocol  = min(ocol0, WW - 4);
    const float om    = (l <= 59 && ocol0 <= WW - 4) ? 1.f : 0.f;
    const int   aR1 = ((l + 1) & 63) << 2;
    const int   aR2 = ((l + 2) & 63) << 2;

    float4 fa[2], fb[4][2];
    {
        const int r0 = rcl(y0 - 3), r1 = rcl(y0 - 2);
        fa[0] = *(const float4*)&acp[r0 * WW + bcol];
        fa[1] = *(const float4*)&acp[r1 * WW + bcol];
        #pragma unroll
        for (int j = 0; j < 4; ++j) {
            fb[j][0] = *(const float4*)&bcp[j][r0 * WW + bcol];
            fb[j][1] = *(const float4*)&bcp[j][r1 * WW + bcol];
        }
    }

    float4 ring[4][8], Vp[4], psj[4];
    float4 psi = make_float4(0,0,0,0), xs = make_float4(0,0,0,0);
    #pragma unroll
    for (int j = 0; j < 4; ++j) {
        Vp[j] = make_float4(0,0,0,0);
        psj[j] = make_float4(0,0,0,0);
        #pragma unroll
        for (int k = 0; k < 8; ++k) ring[j][k] = make_float4(0,0,0,0);
    }

    auto step = [&](const int t, const int kk) {
        const int   c  = y0 - 3 + t;
        const float rm = (c >= 0 && c < HH) ? cmask : 0.f;
        float4 av = fa[kk & 1];
        av = make_float4(av.x*rm, av.y*rm, av.z*rm, av.w*rm);
        float4 bv0 = fb[0][kk & 1], bv1 = fb[1][kk & 1];
        float4 bv2 = fb[2][kk & 1], bv3 = fb[3][kk & 1];
        if (t <= 23) {
            const int rn = rcl(c + 2);
            fa[kk & 1] = *(const float4*)&acp[rn * WW + bcol];
            #pragma unroll
            for (int j = 0; j < 4; ++j)
                fb[j][kk & 1] = *(const float4*)&bcp[j][rn * WW + bcol];
        }
        // vertical-first: ring raw products, winR only at emit
        float4 p;
        p = make_float4(av.x*bv0.x, av.y*bv0.y, av.z*bv0.z, av.w*bv0.w);
        Vp[0].x += p.x - ring[0][kk].x; Vp[0].y += p.y - ring[0][kk].y;
        Vp[0].z += p.z - ring[0][kk].z; Vp[0].w += p.w - ring[0][kk].w; ring[0][kk] = p;
        p = make_float4(av.x*bv1.x, av.y*bv1.y, av.z*bv1.z, av.w*bv1.w);
        Vp[1].x += p.x - ring[1][kk].x; Vp[1].y += p.y - ring[1][kk].y;
        Vp[1].z += p.z - ring[1][kk].z; Vp[1].w += p.w - ring[1][kk].w; ring[1][kk] = p;
        p = make_float4(av.x*bv2.x, av.y*bv2.y, av.z*bv2.z, av.w*bv2.w);
        Vp[2].x += p.x - ring[2][kk].x; Vp[2].y += p.y - ring[2][kk].y;
        Vp[2].z += p.z - ring[2][kk].z; Vp[2].w += p.w - ring[2][kk].w; ring[2][kk] = p;
        p = make_float4(av.x*bv3.x, av.y*bv3.y, av.z*bv3.z, av.w*bv3.w);
        Vp[3].x += p.x - ring[3][kk].x; Vp[3].y += p.y - ring[3][kk].y;
        Vp[3].z += p.z - ring[3][kk].z; Vp[3].w += p.w - ring[3][kk].w; ring[3][kk] = p;

        if (t >= 7) {
            // emit row y = y0+t-7; psi/psj hold row y (loaded LAST step)
            const int   y  = y0 + t - 7;
            const float em = (y < HH) ? om : 0.f;
            float mmx = -1.f, mmy = -1.f, mmz = -1.f, mmw = -1.f;
            #pragma unroll
            for (int j = 0; j < 4; ++j) {
                float4 hj = winR(Vp[j], aR1, aR2);
                float4 sj = psj[j];
                mmx = fmaxf(mmx, hj.x * (psi.x * sj.x));
                mmy = fmaxf(mmy, hj.y * (psi.y * sj.y));
                mmz = fmaxf(mmz, hj.z * (psi.z * sj.z));
                mmw = fmaxf(mmw, hj.w * (psi.w * sj.w));
            }
            xs.x += em * (1.f - fminf(mmx, 1.f));
            xs.y += em * (1.f - fminf(mmy, 1.f));
            xs.z += em * (1.f - fminf(mmz, 1.f));
            xs.w += em * (1.f - fminf(mmw, 1.f));
        }
        if (t >= 6 && t <= 24) {             // prefetch for NEXT step's emit
            const int yn = min(y0 + t - 6, HH - 1);
            psi = *(const float4*)&sip[yn * WW + ocol];
            #pragma unroll
            for (int j = 0; j < 4; ++j)
                psj[j] = *(const float4*)&sjp[j][yn * WW + ocol];
        }
    };
    for (int it = 0; it < 3; ++it) {
        const int t0 = it * 8;
        #pragma unroll
        for (int kk = 0; kk < 8; ++kk) step(t0 + kk, kk);
    }
    step(24, 0); step(25, 1);

    float xt = xs.x + xs.y + xs.z + xs.w;
    #pragma unroll
    for (int off = 32; off > 0; off >>= 1) xt += __shfl_down(xt, off);
    if (l == 0) {
        atomicAdd(&out[1 + z], xt * (1.f / (float)HW));
        atomicAdd(&out[0],     xt * (1.f / (24.f * (float)HW)));
    }
}

extern "C" void kernel_launch(void* const* d_in, const int* in_sizes, int n_in,
                              void* d_out, int out_size, void* d_ws, size_t ws_size,
                              hipStream_t stream) {
    const float* outs = (const float*)d_in[0];   // (4,6,512,512)
    const float* labs = (const float*)d_in[1];   // (4,4,512,512)
    float* out = (float*)d_out;                  // 25 floats
    float* ws  = (float*)d_ws;

    float* acw = ws;                 // 40*HW (a:0..23, b:24..39)
    float* rsw = ws + 40 * HW;       // 40*HW  (1/sqrt of variance box)

    // prep: 3 strips x 16 segs(32 rows) x 40 images (also zeroes out)
    prep_f4<<<dim3(3, 16, 40), 64, 0, stream>>>(outs, labs, acw, rsw, out);
    // main: 3 strips x 27 segs(19 rows) x 24 (b,i) = 1944 waves (one batch)
    ncc_f4<<<dim3(3, 27, 24), 64, 0, stream>>>(acw, rsw, out);
}

// Round 3
// 161.697 us; speedup vs baseline: 2.2315x; 1.0579x over previous
//
#include <hip/hip_runtime.h>

#define HH 512
#define WW 512
#define HW (HH*WW)
#define EPV 1e-20f

// Box window for center (y,x): rows y-3..y+4, cols x-3..x+4, zero-padded.
// 4 cols/lane (float4). Horizontal windows via prefix/suffix exchange:
//   winC(u) = sum_{d=-3..+4} v(u+d)  (centered, 7 bp)  -- mean window
//   winR(u) = sum_{d=1..8}  v(u+d)  (right,    5 bp)  -- box for out col x0+u
// Vertical = register rings (depth 8) of RAW values (vertical-first);
// horizontal winR applied only on emit rows.
// R12: explicit XCD-chunked block swizzle for ncc (R11's FETCH 61->153MB
// regression root-caused to z-stride 81 mod 8 != 0 scattering b-group reuse
// across XCDs); psi/psj prefetch depth 2; prep src fifo depth 4.

__device__ __forceinline__ float bpl(int addr, float v) {
    return __int_as_float(__builtin_amdgcn_ds_bpermute(addr, __float_as_int(v)));
}
__device__ __forceinline__ int rcl(int r) { return min(max(r, 0), HH - 1); }

// centered window over strip cols u=4*lane+e
__device__ __forceinline__ float4 winC(float4 v, int aL1, int aR1) {
    float pre2 = v.x + v.y, pre3 = pre2 + v.z, g = pre3 + v.w;
    float suf2 = v.z + v.w, suf3 = v.y + suf2;
    float Ls1 = bpl(aL1, v.w), Ls2 = bpl(aL1, suf2), Ls3 = bpl(aL1, suf3);
    float Rp1 = bpl(aR1, v.x), Rp2 = bpl(aR1, pre2), Rp3 = bpl(aR1, pre3);
    float Rg  = bpl(aR1, g);
    return make_float4(Ls3 + g + Rp1, Ls2 + g + Rp2, Ls1 + g + Rp3, g + Rg);
}
// right-leaning window (serves output col x0+u)
__device__ __forceinline__ float4 winR(float4 v, int aR1, int aR2) {
    float pre2 = v.x + v.y, pre3 = pre2 + v.z, g = pre3 + v.w;
    float suf2 = v.z + v.w, suf3 = v.y + suf2;
    float G1 = bpl(aR1, g);
    float P1 = bpl(aR2, v.x), P2 = bpl(aR2, pre2), P3 = bpl(aR2, pre3);
    float G2 = bpl(aR2, g);
    return make_float4(suf3 + G1 + P1, suf2 + G1 + P2, v.w + G1 + P3, G1 + G2);
}

// ---------------- prep: raw image -> centered (ac) + 1/sqrt(var box) ------
// One wave per (z, strip, 32-row seg). Strips x0 = {0,232,468}. 48 steps
// (rolled 6x8). Vertical-first for the variance path. FIFO depth 4.
__global__ __launch_bounds__(64) void prep_f4(
    const float* __restrict__ outs, const float* __restrict__ labs,
    float* __restrict__ ac, float* __restrict__ rs, float* __restrict__ outbuf)
{
    const int l  = threadIdx.x;
    if (blockIdx.x == 0 && blockIdx.y == 0 && blockIdx.z == 0 && l < 25)
        outbuf[l] = 0.f;                      // replaces hipMemsetAsync
    const int s  = blockIdx.x;
    const int x0 = (s == 0) ? 0 : (s == 1 ? 232 : 468);
    const int y0 = 32 * blockIdx.y;
    const int z  = blockIdx.z;

    const float* src = (z < 24) ? outs + z * HW : labs + (z - 24) * HW;
    float* acd = ac + z * HW;
    float* rsd = rs + z * HW;

    const int   bcol0 = x0 - 4 + 4 * l;
    const int   bcol  = min(max(bcol0, 0), WW - 4);
    const float cmask = (bcol0 >= 0 && bcol0 <= WW - 4) ? 1.f : 0.f;
    const int   ocol0 = x0 + 4 * l;
    const int   aL1 = ((l - 1) & 63) << 2;
    const int   aR1 = ((l + 1) & 63) << 2;
    const int   aR2 = ((l + 2) & 63) << 2;
    const bool stA = (l >= 1 && l <= 60 && bcol0 >= 0 && bcol0 <= WW - 4);
    const bool stS = (l >= ((x0 == 0) ? 0 : 1) && l <= 59 && ocol0 <= WW - 4);

    float4 fifo[4];
    fifo[0] = *(const float4*)&src[rcl(y0 - 7) * WW + bcol];
    fifo[1] = *(const float4*)&src[rcl(y0 - 6) * WW + bcol];
    fifo[2] = *(const float4*)&src[rcl(y0 - 5) * WW + bcol];
    fifo[3] = *(const float4*)&src[rcl(y0 - 4) * WW + bcol];

    float4 araw[4], haR[8], rgS[8];
    float4 VA = make_float4(0,0,0,0), Vq = make_float4(0,0,0,0);
    #pragma unroll
    for (int k = 0; k < 4; ++k) araw[k] = make_float4(0,0,0,0);
    #pragma unroll
    for (int k = 0; k < 8; ++k) { haR[k] = make_float4(0,0,0,0); rgS[k] = make_float4(0,0,0,0); }

    auto step = [&](const int t, const int kk) {
        const int   r  = y0 - 7 + t;
        const float rm = (r >= 0 && r < HH) ? cmask : 0.f;
        float4 raw = fifo[kk & 3];
        float4 av  = make_float4(raw.x*rm, raw.y*rm, raw.z*rm, raw.w*rm);
        if (t <= 43) fifo[kk & 3] = *(const float4*)&src[rcl(r + 4) * WW + bcol];

        float4 h = winC(av, aL1, aR1);
        VA.x += h.x - haR[kk].x; VA.y += h.y - haR[kk].y;
        VA.z += h.z - haR[kk].z; VA.w += h.w - haR[kk].w;
        haR[kk] = h;

        float4 aold = araw[kk & 3]; araw[kk & 3] = av;   // row c = r-4
        const int   c  = r - 4;
        const float cm = (c >= 0 && c < HH) ? cmask : 0.f;
        float4 acv = make_float4((aold.x - VA.x*(1.f/64.f))*cm,
                                 (aold.y - VA.y*(1.f/64.f))*cm,
                                 (aold.z - VA.z*(1.f/64.f))*cm,
                                 (aold.w - VA.w*(1.f/64.f))*cm);
        if (t >= 11 && t <= 42) {
            if (stA) *(float4*)&acd[c * WW + bcol0] = acv;
        }
        float4 sq = make_float4(acv.x*acv.x, acv.y*acv.y, acv.z*acv.z, acv.w*acv.w);
        Vq.x += sq.x - rgS[kk].x; Vq.y += sq.y - rgS[kk].y;
        Vq.z += sq.z - rgS[kk].z; Vq.w += sq.w - rgS[kk].w;
        rgS[kk] = sq;
        if (t >= 15 && t <= 46) {                        // emit row y = c-4
            const int y = c - 4;                         // y in [y0, y0+31]
            float4 h2 = winR(Vq, aR1, aR2);              // box sum of sq
            if (stS) *(float4*)&rsd[y * WW + ocol0] = make_float4(
                __frsqrt_rn(fmaxf(h2.x, EPV)), __frsqrt_rn(fmaxf(h2.y, EPV)),
                __frsqrt_rn(fmaxf(h2.z, EPV)), __frsqrt_rn(fmaxf(h2.w, EPV)));
        }
    };
    for (int it = 0; it < 6; ++it) {
        const int t0 = it * 8;
        #pragma unroll
        for (int kk = 0; kk < 8; ++kk) step(t0 + kk, kk);
    }
}

// ---------------- main: product boxes, all 4 j per wave, barrier-free -----
// One wave per (z=b*6+i, strip x0={0,240,480}, 19-row seg). 26 steps
// (rolled 3x8 + 2 tail). 1944 waves, XCD-chunked: XCD k owns z in
// {3k,3k+1,3k+2} so b-group reads are L2-local and concurrent.
__global__ __launch_bounds__(64) void ncc_f4(
    const float* __restrict__ ac, const float* __restrict__ rs,
    float* __restrict__ out)
{
    const int l   = threadIdx.x;
    const int n   = blockIdx.x;            // 0..1943
    const int xcd = n & 7;                 // block n -> XCD n%8 (round-robin)
    const int p   = n >> 3;                // 0..242 within XCD
    const int zq  = p / 81;                // 0..2
    const int rem = p - 81 * zq;           // 0..80
    const int seg = rem / 3;               // 0..26
    const int stp = rem - 3 * seg;         // 0..2
    const int x0  = 240 * stp;
    const int y0  = 19 * seg;
    const int z   = 3 * xcd + zq;          // b*6 + i
    const int b   = z / 6;

    const float* acp = ac + z * HW;
    const float* sip = rs + z * HW;
    const float* bcp[4]; const float* sjp[4];
    #pragma unroll
    for (int j = 0; j < 4; ++j) {
        bcp[j] = ac + (24 + b * 4 + j) * HW;
        sjp[j] = rs + (24 + b * 4 + j) * HW;
    }

    const int   bcol0 = x0 - 4 + 4 * l;
    const int   bcol  = min(max(bcol0, 0), WW - 4);
    const float cmask = (bcol0 >= 0 && bcol0 <= WW - 4) ? 1.f : 0.f;
    const int   ocol0 = x0 + 4 * l;
    const int   ocol  = min(ocol0, WW - 4);
    const float om    = (l <= 59 && ocol0 <= WW - 4) ? 1.f : 0.f;
    const int   aR1 = ((l + 1) & 63) << 2;
    const int   aR2 = ((l + 2) & 63) << 2;

    float4 fa[2], fb[4][2];
    {
        const int r0 = rcl(y0 - 3), r1 = rcl(y0 - 2);
        fa[0] = *(const float4*)&acp[r0 * WW + bcol];
        fa[1] = *(const float4*)&acp[r1 * WW + bcol];
        #pragma unroll
        for (int j = 0; j < 4; ++j) {
            fb[j][0] = *(const float4*)&bcp[j][r0 * WW + bcol];
            fb[j][1] = *(const float4*)&bcp[j][r1 * WW + bcol];
        }
    }

    float4 ring[4][8], Vp[4];
    float4 psiB[2], psjB[2][4];
    float4 xs = make_float4(0,0,0,0);
    #pragma unroll
    for (int j = 0; j < 4; ++j) {
        Vp[j] = make_float4(0,0,0,0);
        #pragma unroll
        for (int k = 0; k < 8; ++k) ring[j][k] = make_float4(0,0,0,0);
    }
    #pragma unroll
    for (int q = 0; q < 2; ++q) {
        psiB[q] = make_float4(0,0,0,0);
        #pragma unroll
        for (int j = 0; j < 4; ++j) psjB[q][j] = make_float4(0,0,0,0);
    }

    auto step = [&](const int t, const int kk) {
        const int   c  = y0 - 3 + t;
        const float rm = (c >= 0 && c < HH) ? cmask : 0.f;
        float4 av = fa[kk & 1];
        av = make_float4(av.x*rm, av.y*rm, av.z*rm, av.w*rm);
        float4 bv0 = fb[0][kk & 1], bv1 = fb[1][kk & 1];
        float4 bv2 = fb[2][kk & 1], bv3 = fb[3][kk & 1];
        if (t <= 23) {
            const int rn = rcl(c + 2);
            fa[kk & 1] = *(const float4*)&acp[rn * WW + bcol];
            #pragma unroll
            for (int j = 0; j < 4; ++j)
                fb[j][kk & 1] = *(const float4*)&bcp[j][rn * WW + bcol];
        }
        // vertical-first: ring raw products, winR only at emit
        float4 p4;
        p4 = make_float4(av.x*bv0.x, av.y*bv0.y, av.z*bv0.z, av.w*bv0.w);
        Vp[0].x += p4.x - ring[0][kk].x; Vp[0].y += p4.y - ring[0][kk].y;
        Vp[0].z += p4.z - ring[0][kk].z; Vp[0].w += p4.w - ring[0][kk].w; ring[0][kk] = p4;
        p4 = make_float4(av.x*bv1.x, av.y*bv1.y, av.z*bv1.z, av.w*bv1.w);
        Vp[1].x += p4.x - ring[1][kk].x; Vp[1].y += p4.y - ring[1][kk].y;
        Vp[1].z += p4.z - ring[1][kk].z; Vp[1].w += p4.w - ring[1][kk].w; ring[1][kk] = p4;
        p4 = make_float4(av.x*bv2.x, av.y*bv2.y, av.z*bv2.z, av.w*bv2.w);
        Vp[2].x += p4.x - ring[2][kk].x; Vp[2].y += p4.y - ring[2][kk].y;
        Vp[2].z += p4.z - ring[2][kk].z; Vp[2].w += p4.w - ring[2][kk].w; ring[2][kk] = p4;
        p4 = make_float4(av.x*bv3.x, av.y*bv3.y, av.z*bv3.z, av.w*bv3.w);
        Vp[3].x += p4.x - ring[3][kk].x; Vp[3].y += p4.y - ring[3][kk].y;
        Vp[3].z += p4.z - ring[3][kk].z; Vp[3].w += p4.w - ring[3][kk].w; ring[3][kk] = p4;

        if (t >= 7) {
            // emit row y = y0+t-7; psiB[t&1] holds row y (loaded 2 steps ago)
            const int   y  = y0 + t - 7;
            const float em = (y < HH) ? om : 0.f;
            const float4 psi = psiB[t & 1];
            float mmx = -1.f, mmy = -1.f, mmz = -1.f, mmw = -1.f;
            #pragma unroll
            for (int j = 0; j < 4; ++j) {
                float4 hj = winR(Vp[j], aR1, aR2);
                float4 sj = psjB[t & 1][j];
                mmx = fmaxf(mmx, hj.x * (psi.x * sj.x));
                mmy = fmaxf(mmy, hj.y * (psi.y * sj.y));
                mmz = fmaxf(mmz, hj.z * (psi.z * sj.z));
                mmw = fmaxf(mmw, hj.w * (psi.w * sj.w));
            }
            xs.x += em * (1.f - fminf(mmx, 1.f));
            xs.y += em * (1.f - fminf(mmy, 1.f));
            xs.z += em * (1.f - fminf(mmz, 1.f));
            xs.w += em * (1.f - fminf(mmw, 1.f));
        }
        if (t >= 5 && t <= 23) {             // prefetch row y(t+2), 2-step slack
            const int yn = min(y0 + t - 5, HH - 1);
            psiB[t & 1] = *(const float4*)&sip[yn * WW + ocol];
            #pragma unroll
            for (int j = 0; j < 4; ++j)
                psjB[t & 1][j] = *(const float4*)&sjp[j][yn * WW + ocol];
        }
    };
    for (int it = 0; it < 3; ++it) {
        const int t0 = it * 8;
        #pragma unroll
        for (int kk = 0; kk < 8; ++kk) step(t0 + kk, kk);
    }
    step(24, 0); step(25, 1);

    float xt = xs.x + xs.y + xs.z + xs.w;
    #pragma unroll
    for (int off = 32; off > 0; off >>= 1) xt += __shfl_down(xt, off);
    if (l == 0) {
        atomicAdd(&out[1 + z], xt * (1.f / (float)HW));
        atomicAdd(&out[0],     xt * (1.f / (24.f * (float)HW)));
    }
}

extern "C" void kernel_launch(void* const* d_in, const int* in_sizes, int n_in,
                              void* d_out, int out_size, void* d_ws, size_t ws_size,
                              hipStream_t stream) {
    const float* outs = (const float*)d_in[0];   // (4,6,512,512)
    const float* labs = (const float*)d_in[1];   // (4,4,512,512)
    float* out = (float*)d_out;                  // 25 floats
    float* ws  = (float*)d_ws;

    float* acw = ws;                 // 40*HW (a:0..23, b:24..39)
    float* rsw = ws + 40 * HW;       // 40*HW  (1/sqrt of variance box)

    // prep: 3 strips x 16 segs(32 rows) x 40 images (also zeroes out)
    prep_f4<<<dim3(3, 16, 40), 64, 0, stream>>>(outs, labs, acw, rsw, out);
    // main: 1944 blocks, XCD-chunked decode inside the kernel
    ncc_f4<<<dim3(1944, 1, 1), 64, 0, stream>>>(acw, rsw, out);
}